// Round 1
// baseline (321.990 us; speedup 1.0000x reference)
//
#include <hip/hip_runtime.h>

#define T_FRAMES 32768
#define ROWF 1629          // 543*3 floats per frame
#define NSEG 512
#define NVAL 122           // 42 hand + 80 lips values per frame
#define STRIDE 128         // stage row stride (floats)

// -------------------------------------------------------------------------
// K1: per-frame keep flag + lips finite-stats + stage 122 values per frame.
// One wave (64 lanes) per frame; block = 256 threads = 4 waves.
// -------------------------------------------------------------------------
__global__ __launch_bounds__(256) void k1_keep_stats(
    const float* __restrict__ frames, const int* __restrict__ lips_idx,
    int* __restrict__ keep, float* __restrict__ lip_sum,
    int* __restrict__ lip_cnt, float* __restrict__ stage) {
  __shared__ float ls[80];
  __shared__ int lc[80];
  int tid = threadIdx.x;
  if (tid < 80) { ls[tid] = 0.0f; lc[tid] = 0; }
  __syncthreads();

  int lane = tid & 63;
  int wid = tid >> 6;                         // 0..3
  int wpb = blockDim.x >> 6;                  // waves per block
  int wpg = gridDim.x * wpb;                  // waves per grid

  for (int t = blockIdx.x * wpb + wid; t < T_FRAMES; t += wpg) {
    const float* f = frames + (size_t)t * ROWF;
    float* srow = stage + (size_t)t * STRIDE;

    // ---- hand: lane = j*2 + c for j in [0,21), c in {0,1} ----
    float hv = 0.0f;
    if (lane < 42) {
      int j = lane >> 1, c = lane & 1;
      float lh = f[(468 + j) * 3 + c];
      float rh = f[(522 + j) * 3 + c];
      float a = (c == 0) ? lh : (1.0f - lh);  // lh: [x, 1-y]
      float b = 1.0f - rh;                    // rh: [1-x, 1-y]
      a = (a == a) ? a : 0.0f;                // nan_to_num
      b = (b == b) ? b : 0.0f;
      hv = a + b;
      srow[lane] = hv;
    }
    // wave-reduce the 42 hand values (others contribute 0)
    float s = hv;
    #pragma unroll
    for (int off = 32; off > 0; off >>= 1) s += __shfl_down(s, off);
    s = __shfl(s, 0);
    int kp = (s != 0.0f) ? 1 : 0;
    if (lane == 0) keep[t] = kp;

    // ---- lips: v = j*2 + c for j in [0,40), c in {0,1} ----
    #pragma unroll
    for (int p = 0; p < 2; ++p) {
      int v = lane + p * 64;
      if (v < 80) {
        int j = v >> 1, c = v & 1;
        float x = f[lips_idx[j] * 3 + c];
        srow[42 + v] = x;                     // NaN preserved for K3
        if (kp && (x == x)) {
          atomicAdd(&ls[v], x);
          atomicAdd(&lc[v], 1);
        }
      }
    }
  }
  __syncthreads();
  if (tid < 80) {
    atomicAdd(&lip_sum[tid], ls[tid]);
    atomicAdd(&lip_cnt[tid], lc[tid]);
  }
}

// -------------------------------------------------------------------------
// K2: single-block prefix scan of keep[] -> compacted kept_t[], total S.
// -------------------------------------------------------------------------
__global__ __launch_bounds__(1024) void k2_scan(const int* __restrict__ keep,
                                                int* __restrict__ kept_t,
                                                int* __restrict__ Sp) {
  __shared__ int wsum[16];
  int tid = threadIdx.x;
  const int PER = T_FRAMES / 1024;            // 32
  int base = tid * PER;
  int fl[PER];
  int local = 0;
  #pragma unroll
  for (int k = 0; k < PER; ++k) { fl[k] = keep[base + k]; local += fl[k]; }

  int lane = tid & 63, wid = tid >> 6;
  int scan = local;
  #pragma unroll
  for (int off = 1; off < 64; off <<= 1) {
    int n = __shfl_up(scan, off);
    if (lane >= off) scan += n;
  }
  if (lane == 63) wsum[wid] = scan;
  __syncthreads();
  if (tid < 16) {
    int v = wsum[tid];
    #pragma unroll
    for (int off = 1; off < 16; off <<= 1) {
      int n = __shfl_up(v, off);
      if (tid >= off) v += n;
    }
    wsum[tid] = v;
  }
  __syncthreads();
  int excl = ((wid == 0) ? 0 : wsum[wid - 1]) + (scan - local);
  #pragma unroll
  for (int k = 0; k < PER; ++k) {
    if (fl[k]) kept_t[excl++] = base + k;
  }
  if (tid == 1023) Sp[0] = wsum[15];
}

// -------------------------------------------------------------------------
// K3: one block per segment. Segment i owns kept ranks [b[i], b[i+1)) with
// b[i] = (i*(S-1))>>9 (exact vs np.linspace->int32). Rank S-1 (seg 512) is
// dropped, matching JAX segment_sum OOB-drop. Reads coalesced stage rows.
// -------------------------------------------------------------------------
__global__ __launch_bounds__(256) void k3_segments(
    const float* __restrict__ stage, const int* __restrict__ kept_t,
    const int* __restrict__ Sp, const float* __restrict__ lip_sum,
    const int* __restrict__ lip_cnt, float* __restrict__ out, int out_size) {
  __shared__ int seglist[128];
  __shared__ float part[NVAL];
  int tid = threadIdx.x;
  int v = tid & 127;                          // value index 0..127 (122 used)
  int r = tid >> 7;                           // 0 or 1
  int seg = blockIdx.x;
  long long Sm1 = (long long)Sp[0] - 1;
  if (Sm1 < 0) Sm1 = 0;
  int lo = (int)(((long long)seg * Sm1) >> 9);
  int hi = (int)(((long long)(seg + 1) * Sm1) >> 9);
  int cnt = hi - lo;

  for (int k = tid; k < cnt; k += 256) seglist[k] = kept_t[lo + k];
  __syncthreads();

  float cm = 0.0f;                            // column mean (lips only)
  if (v >= 42 && v < NVAL) {
    int w = v - 42;
    int c = lip_cnt[w];
    cm = (c == 0) ? 0.0f : lip_sum[w] / (float)c;
  }

  float acc = 0.0f;
  if (v < NVAL) {
    for (int k = r; k < cnt; k += 2) {
      float x = stage[(size_t)seglist[k] * STRIDE + v];
      acc += (x == x) ? x : cm;               // hand values never NaN
    }
  }
  if (r == 0 && v < NVAL) part[v] = acc;
  __syncthreads();
  if (r == 1 && v < NVAL) part[v] += acc;
  __syncthreads();
  if (r == 0 && v < NVAL) {
    float mean = (cnt == 0) ? 0.0f : part[v] / (float)cnt;
    int o = seg * NVAL + v;
    if (o < out_size) out[o] = mean;
  }
}

// -------------------------------------------------------------------------
extern "C" void kernel_launch(void* const* d_in, const int* in_sizes, int n_in,
                              void* d_out, int out_size, void* d_ws, size_t ws_size,
                              hipStream_t stream) {
  const float* frames = (const float*)d_in[0];
  const int* lips_idx = (const int*)d_in[1];
  float* out = (float*)d_out;

  char* ws = (char*)d_ws;
  int* keep     = (int*)(ws);                            // 32768*4 = 131072 B
  int* kept_t   = (int*)(ws + 131072);                   // 131072 B
  int* Sp       = (int*)(ws + 262144);                   // 4 B (pad to 64)
  float* lip_sum = (float*)(ws + 262144 + 64);           // 320 B
  int* lip_cnt   = (int*)(ws + 262144 + 64 + 320);       // 320 B
  float* stage   = (float*)(ws + 262144 + 1024);         // 32768*128*4 = 16 MiB

  // accumulators must start at zero (ws is poisoned before every call)
  hipMemsetAsync(lip_sum, 0, 640, stream);

  k1_keep_stats<<<512, 256, 0, stream>>>(frames, lips_idx, keep, lip_sum,
                                         lip_cnt, stage);
  k2_scan<<<1, 1024, 0, stream>>>(keep, kept_t, Sp);
  k3_segments<<<NSEG, 256, 0, stream>>>(stage, kept_t, Sp, lip_sum, lip_cnt,
                                        out, out_size);
}

// Round 2
// 320.354 us; speedup vs baseline: 1.0051x; 1.0051x over previous
//
#include <hip/hip_runtime.h>

#define T_FRAMES 32768
#define ROWF 1629          // 543*3 floats per frame
#define NSEG 512
#define NVAL 122           // 42 hand + 80 lips values per frame
#define STRIDE 128         // stage row stride (floats)
#define PADI 16            // accumulator padding: one per 64B cacheline

// -------------------------------------------------------------------------
// K1: one frame per wave (32768 waves total). Computes keep flag, stages
// 122 resolved values per frame, block-accumulates lips finite-stats in LDS,
// then 160 cacheline-padded global atomics per block.
// -------------------------------------------------------------------------
__global__ __launch_bounds__(1024) void k1_keep_stats(
    const float* __restrict__ frames, const int* __restrict__ lips_idx,
    int* __restrict__ keep, float* __restrict__ lip_sum,
    int* __restrict__ lip_cnt, float* __restrict__ stage) {
  __shared__ float ls[80];
  __shared__ int lc[80];
  int tid = threadIdx.x;
  if (tid < 80) { ls[tid] = 0.0f; lc[tid] = 0; }
  __syncthreads();

  int lane = tid & 63;
  int wid = tid >> 6;                         // 0..15
  int t = blockIdx.x * 16 + wid;              // one frame per wave
  const float* f = frames + (size_t)t * ROWF;
  float* srow = stage + (size_t)t * STRIDE;

  // ---- hand: lane = j*2 + c for j in [0,21), c in {0,1} ----
  float hv = 0.0f;
  if (lane < 42) {
    int j = lane >> 1, c = lane & 1;
    float lh = f[(468 + j) * 3 + c];
    float rh = f[(522 + j) * 3 + c];
    float a = (c == 0) ? lh : (1.0f - lh);    // lh: [x, 1-y]
    float b = 1.0f - rh;                      // rh: [1-x, 1-y]
    a = (a == a) ? a : 0.0f;                  // nan_to_num
    b = (b == b) ? b : 0.0f;
    hv = a + b;
    srow[lane] = hv;
  }
  // wave-reduce the 42 hand values (others contribute 0)
  float s = hv;
  #pragma unroll
  for (int off = 32; off > 0; off >>= 1) s += __shfl_down(s, off);
  s = __shfl(s, 0);
  int kp = (s != 0.0f) ? 1 : 0;
  if (lane == 0) keep[t] = kp;

  // ---- lips: v = j*2 + c for j in [0,40), c in {0,1} ----
  #pragma unroll
  for (int p = 0; p < 2; ++p) {
    int v = lane + p * 64;
    if (v < 80) {
      int j = v >> 1, c = v & 1;
      float x = f[lips_idx[j] * 3 + c];
      srow[42 + v] = x;                       // NaN preserved for K3
      if (kp && (x == x)) {
        atomicAdd(&ls[v], x);
        atomicAdd(&lc[v], 1);
      }
    }
  }
  __syncthreads();
  if (tid < 80) {
    atomicAdd(&lip_sum[tid * PADI], ls[tid]);   // padded: 1 accum / cacheline
    atomicAdd(&lip_cnt[tid * PADI], lc[tid]);
  }
}

// -------------------------------------------------------------------------
// K2: single-block prefix scan of keep[] -> compacted kept_t[], total S.
// -------------------------------------------------------------------------
__global__ __launch_bounds__(1024) void k2_scan(const int* __restrict__ keep,
                                                int* __restrict__ kept_t,
                                                int* __restrict__ Sp) {
  __shared__ int wsum[16];
  int tid = threadIdx.x;
  const int PER = T_FRAMES / 1024;            // 32
  int base = tid * PER;
  int fl[PER];
  int local = 0;
  #pragma unroll
  for (int k = 0; k < PER; ++k) { fl[k] = keep[base + k]; local += fl[k]; }

  int lane = tid & 63, wid = tid >> 6;
  int scan = local;
  #pragma unroll
  for (int off = 1; off < 64; off <<= 1) {
    int n = __shfl_up(scan, off);
    if (lane >= off) scan += n;
  }
  if (lane == 63) wsum[wid] = scan;
  __syncthreads();
  if (tid < 16) {
    int v = wsum[tid];
    #pragma unroll
    for (int off = 1; off < 16; off <<= 1) {
      int n = __shfl_up(v, off);
      if (tid >= off) v += n;
    }
    wsum[tid] = v;
  }
  __syncthreads();
  int excl = ((wid == 0) ? 0 : wsum[wid - 1]) + (scan - local);
  #pragma unroll
  for (int k = 0; k < PER; ++k) {
    if (fl[k]) kept_t[excl++] = base + k;
  }
  if (tid == 1023) Sp[0] = wsum[15];
}

// -------------------------------------------------------------------------
// K3: one block per segment; 512 threads = 4-way row split × 128 values.
// Segment i owns kept ranks [b[i], b[i+1)) with b[i] = (i*(S-1))>>9 (exact
// vs np.linspace->int32). Rank S-1 (seg 512) is dropped, matching JAX
// segment_sum OOB-drop. Stage rows read fully coalesced.
// -------------------------------------------------------------------------
__global__ __launch_bounds__(512) void k3_segments(
    const float* __restrict__ stage, const int* __restrict__ kept_t,
    const int* __restrict__ Sp, const float* __restrict__ lip_sum,
    const int* __restrict__ lip_cnt, float* __restrict__ out, int out_size) {
  __shared__ int seglist[128];
  __shared__ float part[4][128];
  int tid = threadIdx.x;
  int v = tid & 127;                          // value index 0..127 (122 used)
  int r = tid >> 7;                           // 0..3
  int seg = blockIdx.x;
  long long Sm1 = (long long)Sp[0] - 1;
  if (Sm1 < 0) Sm1 = 0;
  int lo = (int)(((long long)seg * Sm1) >> 9);
  int hi = (int)(((long long)(seg + 1) * Sm1) >> 9);
  int cnt = hi - lo;

  for (int k = tid; k < cnt; k += 512) seglist[k] = kept_t[lo + k];
  __syncthreads();

  float cm = 0.0f;                            // column mean (lips only)
  if (v >= 42 && v < NVAL) {
    int w = v - 42;
    int c = lip_cnt[w * PADI];
    cm = (c == 0) ? 0.0f : lip_sum[w * PADI] / (float)c;
  }

  float acc = 0.0f;
  if (v < NVAL) {
    for (int k = r; k < cnt; k += 4) {
      float x = stage[(size_t)seglist[k] * STRIDE + v];
      acc += (x == x) ? x : cm;               // hand values never NaN
    }
  }
  part[r][v] = acc;
  __syncthreads();
  if (r == 0 && v < NVAL) {
    float tot = part[0][v] + part[1][v] + part[2][v] + part[3][v];
    float mean = (cnt == 0) ? 0.0f : tot / (float)cnt;
    int o = seg * NVAL + v;
    if (o < out_size) out[o] = mean;
  }
}

// -------------------------------------------------------------------------
extern "C" void kernel_launch(void* const* d_in, const int* in_sizes, int n_in,
                              void* d_out, int out_size, void* d_ws, size_t ws_size,
                              hipStream_t stream) {
  const float* frames = (const float*)d_in[0];
  const int* lips_idx = (const int*)d_in[1];
  float* out = (float*)d_out;

  char* ws = (char*)d_ws;
  int* keep      = (int*)(ws);                     // 131072 B
  int* kept_t    = (int*)(ws + 131072);            // 131072 B
  int* Sp        = (int*)(ws + 262144);            // 64 B
  float* lip_sum = (float*)(ws + 262208);          // 80 * 64B = 5120 B
  int* lip_cnt   = (int*)(ws + 267328);            // 80 * 64B = 5120 B
  float* stage   = (float*)(ws + 274432);          // 32768*128*4 = 16 MiB

  // accumulators must start at zero (ws is poisoned before every call)
  hipMemsetAsync((void*)lip_sum, 0, 10240, stream);

  k1_keep_stats<<<2048, 1024, 0, stream>>>(frames, lips_idx, keep, lip_sum,
                                           lip_cnt, stage);
  k2_scan<<<1, 1024, 0, stream>>>(keep, kept_t, Sp);
  k3_segments<<<NSEG, 512, 0, stream>>>(stage, kept_t, Sp, lip_sum, lip_cnt,
                                        out, out_size);
}